// Round 4
// baseline (284.849 us; speedup 1.0000x reference)
//
#include <hip/hip_runtime.h>
#include <stdint.h>
#include <stddef.h>

// Problem constants (fixed by setup_inputs)
#define N_ROWS 500000
#define DDIM   128
#define K2     256      // 2*D
#define KBOND  32
#define TILE_ROWS 64
#define NT ((N_ROWS + TILE_ROWS - 1) / TILE_ROWS)   // 7813
#define MR_CH 64
#define NCH ((NT + MR_CH - 1) / MR_CH)              // 123
#define P2_BLOCKS 2048

typedef float  f32x4  __attribute__((ext_vector_type(4)));
typedef __bf16 bf16x8 __attribute__((ext_vector_type(8)));
typedef __bf16 bf16x4 __attribute__((ext_vector_type(4)));

// ---- module-scope device scratch: no dependence on d_ws/ws_size ----
__device__ __bf16 g_wbf[DDIM * K2];                    // 64 KiB  (W_i_w bf16, [d][k])
__device__ float  g_partials[(size_t)NT * DDIM];       // 4 MiB
__device__ float  g_p2[NCH * DDIM];                    // 63 KiB
__device__ float  g_msg[DDIM];
__device__ __bf16 g_hn[(size_t)N_ROWS * DDIM];         // 128 MiB (h_n bf16)

// ---- kernel 1: W_i_w f32 -> bf16 (natural [d][k] layout) ----
__global__ void k_prep(const float* __restrict__ w) {
  int t = blockIdx.x * blockDim.x + threadIdx.x;
  if (t < DDIM * K2) g_wbf[t] = (__bf16)w[t];          // RNE convert
}

// ---- kernel 2: fused h_n GEMM + m partial accumulation ----
// ONE 64-row tile per block; 512 threads = 8 waves. 4 blocks/CU co-resident
// provide the cross-tile pipelining (no intra-block loop).
// MFMA operands swapped: A = W (rows=d), B = x-data (cols=n).
// D: lane l -> n = l&15, d = 16*w + 4*(l>>4) + reg  (4 consecutive d / lane).
// A/B use the IDENTICAL (g,e)->k map (k = 32ks+8g+e) so any internal hardware
// k-permutation cancels (verified in rounds 2-3).
// LDS A-tile: 64 rows x 256 k bf16, row stride 512 B, 4-bit XOR swizzle:
//   byte(r,k) = r*512 + (2k ^ ((r&15)<<4))
__global__ __launch_bounds__(512)
void k_pass1(const float* __restrict__ x, const float* __restrict__ he,
             const float* __restrict__ bond, const float* __restrict__ bias)
{
  __shared__ __align__(16) unsigned char a_lds[TILE_ROWS * 512];   // 32 KiB
  __shared__ float s_part[8][TILE_ROWS];                           // 2 KiB
  __shared__ float s_lds[TILE_ROWS];

  const int tid  = threadIdx.x;
  const int w    = tid >> 6;        // wave 0..7: owns d in [16w, 16w+16)
  const int lane = tid & 63;
  const int l15  = lane & 15;
  const int g    = lane >> 4;       // 0..3
  const int rb   = blockIdx.x * TILE_ROWS;

  // W A-fragments for this wave, ALL K, in registers (loaded once): 32 VGPRs
  bf16x8 wfrag[8];
  #pragma unroll
  for (int ks = 0; ks < 8; ++ks)
    wfrag[ks] = *(const bf16x8*)(g_wbf + (size_t)(16 * w + l15) * K2 + ks * 32 + 8 * g);

  const int d0 = 16 * w + 4 * g;            // lane's 4 consecutive output cols
  const f32x4 bv = *(const f32x4*)(bias + d0);

  // ---- stage A-tile: 16 threads/row, one ds_write_b128 per thread-iter ----
  #pragma unroll
  for (int it = 0; it < 4; ++it) {
    const int r = ((it & 1) ? 32 : 0) + (tid >> 4);   // 0..63
    const int c = tid & 15;                           // 8-f32 slot within row
    const float* src = (it < 2) ? x : he;
    int n  = rb + r;
    int nc = n < N_ROWS ? n : (N_ROWS - 1);           // clamp (s=0 kills OOB)
    f32x4 v0 = *(const f32x4*)(src + (size_t)nc * DDIM + 8 * c);
    f32x4 v1 = *(const f32x4*)(src + (size_t)nc * DDIM + 8 * c + 4);
    bf16x8 b;
    #pragma unroll
    for (int i = 0; i < 4; ++i) { b[i] = (__bf16)v0[i]; b[4 + i] = (__bf16)v1[i]; }
    const int base = (it < 2) ? 0 : 256;              // he occupies bytes [256,512)
    *(bf16x8*)(a_lds + r * 512 + ((base + 16 * c) ^ ((r & 15) << 4))) = b;
  }

  // ---- bond partials: ALL 8 waves, 4 k's each, coalesced ----
  {
    const int row = tid & 63, kg = tid >> 6;
    int n = rb + row;
    float p = 0.f;
    if (n < N_ROWS) {
      #pragma unroll
      for (int j = 0; j < 4; ++j) p += bond[(size_t)(4 * kg + j) * N_ROWS + n];
    }
    s_part[kg][row] = p;
  }
  __syncthreads();

  // wave 0 finishes s[n] while others start MFMA; barrier 2 publishes it
  if (tid < TILE_ROWS) {
    float s = 0.f;
    #pragma unroll
    for (int kg = 0; kg < 8; ++kg) s += s_part[kg][tid];
    s_lds[tid] = s;
  }

  // ---- MFMA: 4 n-fragments x 8 k-steps ----
  f32x4 acc[4];
  #pragma unroll
  for (int i = 0; i < 4; ++i) acc[i] = (f32x4)(0.f);

  #pragma unroll
  for (int ks = 0; ks < 8; ++ks) {
    bf16x8 bfrag[4];
    #pragma unroll
    for (int nf = 0; nf < 4; ++nf) {
      const int r = 16 * nf + l15;
      bfrag[nf] = *(const bf16x8*)(a_lds + r * 512 +
                                   ((64 * ks + 16 * g) ^ ((r & 15) << 4)));
    }
    #pragma unroll
    for (int nf = 0; nf < 4; ++nf)
      acc[nf] = __builtin_amdgcn_mfma_f32_16x16x32_bf16(wfrag[ks], bfrag[nf],
                                                        acc[nf], 0, 0, 0);
  }
  __syncthreads();   // publish s_lds

  // ---- epilogue: bias+relu, 8-B h_n store, m partial ----
  f32x4 macc = (f32x4)(0.f);
  #pragma unroll
  for (int nf = 0; nf < 4; ++nf) {
    const int lr = 16 * nf + l15;
    const int n  = rb + lr;
    const float sn = s_lds[lr];
    f32x4 h;
    #pragma unroll
    for (int i = 0; i < 4; ++i) {
      float v = acc[nf][i] + bv[i];
      h[i] = v > 0.f ? v : 0.f;
    }
    macc += sn * h;
    if (n < N_ROWS) {
      bf16x4 hb;
      #pragma unroll
      for (int i = 0; i < 4; ++i) hb[i] = (__bf16)h[i];
      *(bf16x4*)(g_hn + (size_t)n * DDIM + d0) = hb;
    }
  }

  // ---- m partial: reduce the 16 l15-lanes (same d0), store f32x4 ----
  #pragma unroll
  for (int off = 1; off <= 8; off <<= 1) {
    #pragma unroll
    for (int i = 0; i < 4; ++i) macc[i] += __shfl_xor(macc[i], off, 64);
  }
  if (l15 == 0)
    *(f32x4*)(&g_partials[(size_t)blockIdx.x * DDIM + d0]) = macc;
}

// ---- kernel 3: coalesced chunk-reduce of partials: NT x 128 -> NCH x 128 ----
__global__ void k_mr1() {
  const int c  = blockIdx.x;                 // chunk of MR_CH rows
  const int r0 = c * MR_CH;
  const int d    = threadIdx.x & 127;
  const int half = threadIdx.x >> 7;         // 0/1
  const int rend = (r0 + MR_CH < NT) ? (r0 + MR_CH) : NT;
  float acc = 0.f;
  for (int r = r0 + half; r < rend; r += 2)
    acc += g_partials[(size_t)r * DDIM + d];
  __shared__ float sp[DDIM];
  if (half == 0) sp[d] = acc;
  __syncthreads();
  if (half == 1) g_p2[c * DDIM + d] = sp[d] + acc;
}

// ---- kernel 4: m[d] = sum_c p2[c][d];  msg = W_m m + b_m ----
__global__ void k_msg(const float* __restrict__ wm, const float* __restrict__ bm) {
  __shared__ float ms[DDIM];
  const int d = threadIdx.x;                 // 128 threads
  float s = 0.f;
  for (int c = 0; c < NCH; ++c) s += g_p2[c * DDIM + d];
  ms[d] = s;
  __syncthreads();
  float acc = bm[d];
  #pragma unroll 8
  for (int j = 0; j < DDIM; ++j) acc += ms[j] * wm[(size_t)d * DDIM + j];
  g_msg[d] = acc;
}

// ---- kernel 5: out = relu(h_n + msg) ----
__global__ __launch_bounds__(256)
void k_pass2(float* __restrict__ out)
{
  __shared__ float ms[DDIM];
  if (threadIdx.x < DDIM) ms[threadIdx.x] = g_msg[threadIdx.x];
  __syncthreads();
  const size_t total = (size_t)N_ROWS * DDIM / 8;   // 8 elems per chunk
  for (size_t c = (size_t)blockIdx.x * blockDim.x + threadIdx.x; c < total;
       c += (size_t)gridDim.x * blockDim.x) {
    const size_t base = c * 8;
    const int col0 = (int)(base & (DDIM - 1));
    bf16x8 hv = *(const bf16x8*)(g_hn + base);
    f32x4 o0, o1;
    #pragma unroll
    for (int i = 0; i < 4; ++i) {
      float a = (float)hv[i]     + ms[col0 + i];
      float b = (float)hv[4 + i] + ms[col0 + 4 + i];
      o0[i] = a > 0.f ? a : 0.f;
      o1[i] = b > 0.f ? b : 0.f;
    }
    *(f32x4*)(out + base)     = o0;
    *(f32x4*)(out + base + 4) = o1;
  }
}

extern "C" void kernel_launch(void* const* d_in, const int* in_sizes, int n_in,
                              void* d_out, int out_size, void* d_ws, size_t ws_size,
                              hipStream_t stream) {
  const float* x    = (const float*)d_in[0];
  const float* he   = (const float*)d_in[1];
  const float* bond = (const float*)d_in[2];
  const float* wi   = (const float*)d_in[3];
  const float* bi   = (const float*)d_in[4];
  const float* wm   = (const float*)d_in[5];
  const float* bm   = (const float*)d_in[6];
  float* out = (float*)d_out;
  (void)d_ws; (void)ws_size;

  k_prep<<<(DDIM * K2 + 255) / 256, 256, 0, stream>>>(wi);
  k_pass1<<<NT, 512, 0, stream>>>(x, he, bond, bi);
  k_mr1<<<NCH, 256, 0, stream>>>();
  k_msg<<<1, 128, 0, stream>>>(wm, bm);
  k_pass2<<<P2_BLOCKS, 256, 0, stream>>>(out);
}